// Round 9
// baseline (212.319 us; speedup 1.0000x reference)
//
#include <hip/hip_runtime.h>
#include <hip/hip_bf16.h>

#define B_     4
#define V_IN   12500
#define V_OUT  50000
#define C_IN   64
#define C_OUT  32
#define SPIRAL 9
#define K_NNZ  3
#define ROWS   (B_ * V_OUT)       // 200000
#define KDIM   (SPIRAL * C_IN)    // 576
#define KSTEPS (KDIM / 32)        // 18 (16x16x32 MFMA)
#define WFRAG_ELEMS (KSTEPS * 2 * 64 * 8)  // 18432 bf16 = 36864 B

#define GROUPS_PER_B (V_OUT / 16) // 3125 16-row groups per batch (k1)
#define G1           2048         // k1 blocks (+1 W-prep); 256 per XCD
#define TILES_PER_B  782          // 781 full 64-row tiles + one 16-row tail (k2)
#define G2           1024         // k2 blocks; 4 blocks/CU resident (16 waves/CU)

typedef __attribute__((ext_vector_type(8))) short short8_t;   // 8 bf16 (4 VGPRs)
typedef __attribute__((ext_vector_type(4))) float floatx4;    // 4 fp32 acc

__device__ __forceinline__ unsigned short f32_to_bf16(float f) {
    unsigned int u = __float_as_uint(f);
    unsigned int r = u + 0x7fffu + ((u >> 16) & 1u);   // round-to-nearest-even
    return (unsigned short)(r >> 16);
}

// ---------------- Kernel 1: upsample, 2-wide ILP ----------------------------
// up[b,v,c] = sum_k x[b,up_idx[v,k],c]*up_val[v,k] -> bf16 in ws.
// XCD-swizzled: block i serves batch b=(i&7)>>1 (x[b]=3.2MB stays in XCD L2).
// Two independent row-groups per iteration -> two overlapping idx->gather
// chains (iterations were serial latency chains before).
// Block G1: rearrange weight (576x32 fp32) into MFMA fragment order (bf16):
//   w_frag[((kstep*2+ntile)*64+lane)*8+j] = W[kstep*32+(lane>>4)*8+j][ntile*16+(lane&15)]
__global__ __launch_bounds__(256) void upsample_kernel(
    const float* __restrict__ x,
    const int* __restrict__ up_idx,
    const float* __restrict__ up_val,
    const float* __restrict__ weight,
    unsigned short* __restrict__ up_bf16,
    unsigned short* __restrict__ w_frag)
{
    int tid = threadIdx.x;
    if (blockIdx.x == G1) {
        for (int idx = tid; idx < WFRAG_ELEMS; idx += 256) {
            int j     = idx & 7;
            int lane  = (idx >> 3) & 63;
            int ntile = (idx >> 9) & 1;
            int kstep = idx >> 10;
            int k = kstep * 32 + (lane >> 4) * 8 + j;
            int n = ntile * 16 + (lane & 15);
            w_frag[idx] = f32_to_bf16(weight[k * C_OUT + n]);
        }
        return;
    }
    int xcd  = blockIdx.x & 7;
    int b    = xcd >> 1;                    // batch owned by this XCD pair
    int h    = xcd & 1;
    int j    = blockIdx.x >> 3;             // [0, 256)
    int slot = h + 2 * j;                   // [0, 512)
    int lane16 = tid & 15;                  // 4 channels each
    int sub    = tid >> 4;                  // row within 16-row group

    const float* xb = x + (size_t)b * V_IN * C_IN;
    unsigned short* upb = up_bf16 + (size_t)b * V_OUT * C_IN;

    for (int gl = slot; gl < GROUPS_PER_B; gl += 1024) {
        int gl2  = gl + 512;
        int has2 = gl2 < GROUPS_PER_B;
        int v1 = gl * 16 + sub;
        int v2 = has2 ? gl2 * 16 + sub : v1;
        // both groups' indices issue together (independent chains)
        int   u10 = up_idx[v1 * K_NNZ + 0], u11 = up_idx[v1 * K_NNZ + 1], u12 = up_idx[v1 * K_NNZ + 2];
        int   u20 = up_idx[v2 * K_NNZ + 0], u21 = up_idx[v2 * K_NNZ + 1], u22 = up_idx[v2 * K_NNZ + 2];
        float c10 = up_val[v1 * K_NNZ + 0], c11 = up_val[v1 * K_NNZ + 1], c12 = up_val[v1 * K_NNZ + 2];
        float c20 = up_val[v2 * K_NNZ + 0], c21 = up_val[v2 * K_NNZ + 1], c22 = up_val[v2 * K_NNZ + 2];
        float4 xa0 = *((const float4*)(xb + (size_t)u10 * C_IN) + lane16);
        float4 xa1 = *((const float4*)(xb + (size_t)u11 * C_IN) + lane16);
        float4 xa2 = *((const float4*)(xb + (size_t)u12 * C_IN) + lane16);
        float4 xb0 = *((const float4*)(xb + (size_t)u20 * C_IN) + lane16);
        float4 xb1 = *((const float4*)(xb + (size_t)u21 * C_IN) + lane16);
        float4 xb2 = *((const float4*)(xb + (size_t)u22 * C_IN) + lane16);
        ushort4 o1, o2;
        o1.x = f32_to_bf16(c10 * xa0.x + c11 * xa1.x + c12 * xa2.x);
        o1.y = f32_to_bf16(c10 * xa0.y + c11 * xa1.y + c12 * xa2.y);
        o1.z = f32_to_bf16(c10 * xa0.z + c11 * xa1.z + c12 * xa2.z);
        o1.w = f32_to_bf16(c10 * xa0.w + c11 * xa1.w + c12 * xa2.w);
        o2.x = f32_to_bf16(c20 * xb0.x + c21 * xb1.x + c22 * xb2.x);
        o2.y = f32_to_bf16(c20 * xb0.y + c21 * xb1.y + c22 * xb2.y);
        o2.z = f32_to_bf16(c20 * xb0.z + c21 * xb1.z + c22 * xb2.z);
        o2.w = f32_to_bf16(c20 * xb0.w + c21 * xb1.w + c22 * xb2.w);
        *((ushort4*)(upb + (size_t)v1 * C_IN) + lane16) = o1;
        if (has2) *((ushort4*)(upb + (size_t)v2 * C_IN) + lane16) = o2;
    }
}

// ---------------- Kernel 2: gather + MFMA gemm, 16 waves/CU -----------------
// y[r,n] = relu( sum_f g[r,f]*W[f,n] + bias[n] ), g[r,s*64+c]=up[b,spiral[v,s],c].
// LDS-resident W, single g-buffer (36 VGPRs), sp prefetched one tile ahead.
// __launch_bounds__(256,4): VGPR<=128 -> 4 blocks/CU co-resident
// (LDS 4x36.9=147<=160 KB) = 16 waves/CU of TLP for the gather latency.
__global__ __launch_bounds__(256, 4) void gemm_kernel(
    const unsigned short* __restrict__ up_bf16,
    const int* __restrict__ spiral,
    const unsigned short* __restrict__ w_frag,
    const float* __restrict__ bias,
    float* __restrict__ out)
{
    __shared__ __align__(16) unsigned short w_lds[WFRAG_ELEMS];  // 36864 B
    int tid = threadIdx.x;
    {   // stage W fragments to LDS once per block
        const uint4* src = (const uint4*)w_frag;
        uint4* dst = (uint4*)w_lds;
#pragma unroll
        for (int i = 0; i < WFRAG_ELEMS / 8 / 256; i++)
            dst[tid + i * 256] = src[tid + i * 256];
    }
    __syncthreads();

    int wave = tid >> 6;
    int lane = tid & 63;
    int m    = lane & 15;
    int quad = lane >> 4;

    int xcd  = blockIdx.x & 7;
    int b    = xcd >> 1;
    int h    = xcd & 1;
    int j    = blockIdx.x >> 3;             // [0, 128)
    int slot = h + 2 * j;                   // [0, 256)

    const unsigned short* upb = up_bf16 + (size_t)b * V_OUT * C_IN;
    float* outb = out + (size_t)b * V_OUT * C_OUT;

    float4 bias0 = ((const float4*)bias)[quad];      // bias[quad*4 .. +3]
    float4 bias1 = ((const float4*)bias)[4 + quad];  // bias[16+quad*4 .. +3]

    // sp prefetch for the first tile
    int sp[SPIRAL];
    {
        int vr = slot * 64 + wave * 16 + m;
        int v = vr < V_OUT ? vr : 0;
#pragma unroll
        for (int s = 0; s < SPIRAL; s++) sp[s] = spiral[v * SPIRAL + s];
    }

    for (int tl = slot; tl < TILES_PER_B; tl += 256) {
        // gather this tile's g-fragments (single buffer, 18 loads in flight)
        short8_t g0[SPIRAL], g1[SPIRAL];
#pragma unroll
        for (int s = 0; s < SPIRAL; s++) {
            const unsigned short* rowp = upb + (size_t)sp[s] * C_IN;
            g0[s] = *(const short8_t*)(rowp + quad * 8);
            g1[s] = *(const short8_t*)(rowp + 32 + quad * 8);
        }
        // prefetch next tile's spiral indices (overlaps the MFMA chain)
        int tln = tl + 256;
        if (tln < TILES_PER_B) {
            int vrn = tln * 64 + wave * 16 + m;
            int vn = vrn < V_OUT ? vrn : 0;
#pragma unroll
            for (int s = 0; s < SPIRAL; s++) sp[s] = spiral[vn * SPIRAL + s];
        }

        floatx4 acc0 = {0.f, 0.f, 0.f, 0.f};
        floatx4 acc1 = {0.f, 0.f, 0.f, 0.f};
#pragma unroll
        for (int kstep = 0; kstep < KSTEPS; kstep++) {
            short8_t gf = (kstep & 1) ? g1[kstep >> 1] : g0[kstep >> 1];
            const short8_t* wp0 = (const short8_t*)(w_lds + ((kstep * 2 + 0) * 64 + lane) * 8);
            const short8_t* wp1 = (const short8_t*)(w_lds + ((kstep * 2 + 1) * 64 + lane) * 8);
            acc0 = __builtin_amdgcn_mfma_f32_16x16x32_bf16(*wp0, gf, acc0, 0, 0, 0);
            acc1 = __builtin_amdgcn_mfma_f32_16x16x32_bf16(*wp1, gf, acc1, 0, 0, 0);
        }

        int vr = tl * 64 + wave * 16 + m;
        if (vr < V_OUT) {
            float4 o0, o1;
            o0.x = acc0[0] + bias0.x; o0.y = acc0[1] + bias0.y;
            o0.z = acc0[2] + bias0.z; o0.w = acc0[3] + bias0.w;
            o1.x = acc1[0] + bias1.x; o1.y = acc1[1] + bias1.y;
            o1.z = acc1[2] + bias1.z; o1.w = acc1[3] + bias1.w;
            o0.x = o0.x > 0.f ? o0.x : 0.f;  o0.y = o0.y > 0.f ? o0.y : 0.f;
            o0.z = o0.z > 0.f ? o0.z : 0.f;  o0.w = o0.w > 0.f ? o0.w : 0.f;
            o1.x = o1.x > 0.f ? o1.x : 0.f;  o1.y = o1.y > 0.f ? o1.y : 0.f;
            o1.z = o1.z > 0.f ? o1.z : 0.f;  o1.w = o1.w > 0.f ? o1.w : 0.f;
            float* op = outb + (size_t)vr * C_OUT;
            *(float4*)(op + quad * 4)      = o0;
            *(float4*)(op + 16 + quad * 4) = o1;
        }
    }
}

extern "C" void kernel_launch(void* const* d_in, const int* in_sizes, int n_in,
                              void* d_out, int out_size, void* d_ws, size_t ws_size,
                              hipStream_t stream) {
    const float* x      = (const float*)d_in[0];
    const int*   spiral = (const int*)d_in[1];
    const int*   up_idx = (const int*)d_in[2];
    const float* up_val = (const float*)d_in[3];
    const float* weight = (const float*)d_in[4];
    const float* bias   = (const float*)d_in[5];
    float* out = (float*)d_out;

    unsigned short* up_ws  = (unsigned short*)d_ws;          // 200000*64 bf16 = 25.6 MB
    unsigned short* w_frag = up_ws + (size_t)ROWS * C_IN;    // + 36864 B

    upsample_kernel<<<G1 + 1, 256, 0, stream>>>(x, up_idx, up_val, weight, up_ws, w_frag);
    gemm_kernel<<<G2, 256, 0, stream>>>(up_ws, spiral, w_frag, bias, out);
}

// Round 10
// 130.363 us; speedup vs baseline: 1.6287x; 1.6287x over previous
//
#include <hip/hip_runtime.h>
#include <hip/hip_bf16.h>

#define B_     4
#define V_IN   12500
#define V_OUT  50000
#define C_IN   64
#define C_OUT  32
#define SPIRAL 9
#define K_NNZ  3
#define ROWS   (B_ * V_OUT)       // 200000
#define KDIM   (SPIRAL * C_IN)    // 576
#define KSTEPS (KDIM / 32)        // 18 (16x16x32 MFMA)
#define WFRAG_ELEMS (KSTEPS * 2 * 64 * 8)  // 18432 bf16 = 36864 B

#define GROUPS_PER_B (V_OUT / 16) // 3125 16-row groups per batch (k1)
#define G1           2048         // k1 blocks (+1 W-prep); 256 per XCD
#define TILES_PER_B  782          // 781 full 64-row tiles + one 16-row tail (k2)
#define G2           1024         // k2 blocks; 4 blocks/CU resident (16 waves/CU)

typedef __attribute__((ext_vector_type(8))) short short8_t;   // 8 bf16 (4 VGPRs)
typedef __attribute__((ext_vector_type(4))) float floatx4;    // 4 fp32 acc

__device__ __forceinline__ unsigned short f32_to_bf16(float f) {
    unsigned int u = __float_as_uint(f);
    unsigned int r = u + 0x7fffu + ((u >> 16) & 1u);   // round-to-nearest-even
    return (unsigned short)(r >> 16);
}

// ---------------- Kernel 1: upsample, 2-wide ILP ----------------------------
// up[b,v,c] = sum_k x[b,up_idx[v,k],c]*up_val[v,k] -> bf16 in ws.
// XCD-swizzled: block i serves batch b=(i&7)>>1 (x[b]=3.2MB stays in XCD L2).
// Block G1: rearrange weight (576x32 fp32) into MFMA fragment order (bf16):
//   w_frag[((kstep*2+ntile)*64+lane)*8+j] = W[kstep*32+(lane>>4)*8+j][ntile*16+(lane&15)]
__global__ __launch_bounds__(256) void upsample_kernel(
    const float* __restrict__ x,
    const int* __restrict__ up_idx,
    const float* __restrict__ up_val,
    const float* __restrict__ weight,
    unsigned short* __restrict__ up_bf16,
    unsigned short* __restrict__ w_frag)
{
    int tid = threadIdx.x;
    if (blockIdx.x == G1) {
        for (int idx = tid; idx < WFRAG_ELEMS; idx += 256) {
            int j     = idx & 7;
            int lane  = (idx >> 3) & 63;
            int ntile = (idx >> 9) & 1;
            int kstep = idx >> 10;
            int k = kstep * 32 + (lane >> 4) * 8 + j;
            int n = ntile * 16 + (lane & 15);
            w_frag[idx] = f32_to_bf16(weight[k * C_OUT + n]);
        }
        return;
    }
    int xcd  = blockIdx.x & 7;
    int b    = xcd >> 1;                    // batch owned by this XCD pair
    int h    = xcd & 1;
    int j    = blockIdx.x >> 3;             // [0, 256)
    int slot = h + 2 * j;                   // [0, 512)
    int lane16 = tid & 15;                  // 4 channels each
    int sub    = tid >> 4;                  // row within 16-row group

    const float* xb = x + (size_t)b * V_IN * C_IN;
    unsigned short* upb = up_bf16 + (size_t)b * V_OUT * C_IN;

    for (int gl = slot; gl < GROUPS_PER_B; gl += 1024) {
        int gl2  = gl + 512;
        int has2 = gl2 < GROUPS_PER_B;
        int v1 = gl * 16 + sub;
        int v2 = has2 ? gl2 * 16 + sub : v1;
        int   u10 = up_idx[v1 * K_NNZ + 0], u11 = up_idx[v1 * K_NNZ + 1], u12 = up_idx[v1 * K_NNZ + 2];
        int   u20 = up_idx[v2 * K_NNZ + 0], u21 = up_idx[v2 * K_NNZ + 1], u22 = up_idx[v2 * K_NNZ + 2];
        float c10 = up_val[v1 * K_NNZ + 0], c11 = up_val[v1 * K_NNZ + 1], c12 = up_val[v1 * K_NNZ + 2];
        float c20 = up_val[v2 * K_NNZ + 0], c21 = up_val[v2 * K_NNZ + 1], c22 = up_val[v2 * K_NNZ + 2];
        float4 xa0 = *((const float4*)(xb + (size_t)u10 * C_IN) + lane16);
        float4 xa1 = *((const float4*)(xb + (size_t)u11 * C_IN) + lane16);
        float4 xa2 = *((const float4*)(xb + (size_t)u12 * C_IN) + lane16);
        float4 xb0 = *((const float4*)(xb + (size_t)u20 * C_IN) + lane16);
        float4 xb1 = *((const float4*)(xb + (size_t)u21 * C_IN) + lane16);
        float4 xb2 = *((const float4*)(xb + (size_t)u22 * C_IN) + lane16);
        ushort4 o1, o2;
        o1.x = f32_to_bf16(c10 * xa0.x + c11 * xa1.x + c12 * xa2.x);
        o1.y = f32_to_bf16(c10 * xa0.y + c11 * xa1.y + c12 * xa2.y);
        o1.z = f32_to_bf16(c10 * xa0.z + c11 * xa1.z + c12 * xa2.z);
        o1.w = f32_to_bf16(c10 * xa0.w + c11 * xa1.w + c12 * xa2.w);
        o2.x = f32_to_bf16(c20 * xb0.x + c21 * xb1.x + c22 * xb2.x);
        o2.y = f32_to_bf16(c20 * xb0.y + c21 * xb1.y + c22 * xb2.y);
        o2.z = f32_to_bf16(c20 * xb0.z + c21 * xb1.z + c22 * xb2.z);
        o2.w = f32_to_bf16(c20 * xb0.w + c21 * xb1.w + c22 * xb2.w);
        *((ushort4*)(upb + (size_t)v1 * C_IN) + lane16) = o1;
        if (has2) *((ushort4*)(upb + (size_t)v2 * C_IN) + lane16) = o2;
    }
}

// ---------------- Kernel 2: gather + MFMA gemm, 16 waves/CU -----------------
// y[r,n] = relu( sum_f g[r,f]*W[f,n] + bias[n] ), g[r,s*64+c]=up[b,spiral[v,s],c].
// LDS-resident W, single g-buffer (72 VGPRs), sp prefetched one tile ahead.
// __launch_bounds__(256,2): empirically caps VGPR at 128 >= live ~110 ->
// no spill; occupancy then LDS-bound at 4 blocks/CU (147<=160 KB) = 16 waves/CU.
__global__ __launch_bounds__(256, 2) void gemm_kernel(
    const unsigned short* __restrict__ up_bf16,
    const int* __restrict__ spiral,
    const unsigned short* __restrict__ w_frag,
    const float* __restrict__ bias,
    float* __restrict__ out)
{
    __shared__ __align__(16) unsigned short w_lds[WFRAG_ELEMS];  // 36864 B
    int tid = threadIdx.x;
    {   // stage W fragments to LDS once per block
        const uint4* src = (const uint4*)w_frag;
        uint4* dst = (uint4*)w_lds;
#pragma unroll
        for (int i = 0; i < WFRAG_ELEMS / 8 / 256; i++)
            dst[tid + i * 256] = src[tid + i * 256];
    }
    __syncthreads();

    int wave = tid >> 6;
    int lane = tid & 63;
    int m    = lane & 15;
    int quad = lane >> 4;

    int xcd  = blockIdx.x & 7;
    int b    = xcd >> 1;
    int h    = xcd & 1;
    int j    = blockIdx.x >> 3;             // [0, 128)
    int slot = h + 2 * j;                   // [0, 256)

    const unsigned short* upb = up_bf16 + (size_t)b * V_OUT * C_IN;
    float* outb = out + (size_t)b * V_OUT * C_OUT;

    float4 bias0 = ((const float4*)bias)[quad];      // bias[quad*4 .. +3]
    float4 bias1 = ((const float4*)bias)[4 + quad];  // bias[16+quad*4 .. +3]

    // sp prefetch for the first tile
    int sp[SPIRAL];
    {
        int vr = slot * 64 + wave * 16 + m;
        int v = vr < V_OUT ? vr : 0;
#pragma unroll
        for (int s = 0; s < SPIRAL; s++) sp[s] = spiral[v * SPIRAL + s];
    }

    for (int tl = slot; tl < TILES_PER_B; tl += 256) {
        // gather this tile's g-fragments (single buffer, 18 loads in flight)
        short8_t g0[SPIRAL], g1[SPIRAL];
#pragma unroll
        for (int s = 0; s < SPIRAL; s++) {
            const unsigned short* rowp = upb + (size_t)sp[s] * C_IN;
            g0[s] = *(const short8_t*)(rowp + quad * 8);
            g1[s] = *(const short8_t*)(rowp + 32 + quad * 8);
        }
        // prefetch next tile's spiral indices (overlaps the MFMA chain)
        int tln = tl + 256;
        if (tln < TILES_PER_B) {
            int vrn = tln * 64 + wave * 16 + m;
            int vn = vrn < V_OUT ? vrn : 0;
#pragma unroll
            for (int s = 0; s < SPIRAL; s++) sp[s] = spiral[vn * SPIRAL + s];
        }

        floatx4 acc0 = {0.f, 0.f, 0.f, 0.f};
        floatx4 acc1 = {0.f, 0.f, 0.f, 0.f};
#pragma unroll
        for (int kstep = 0; kstep < KSTEPS; kstep++) {
            short8_t gf = (kstep & 1) ? g1[kstep >> 1] : g0[kstep >> 1];
            const short8_t* wp0 = (const short8_t*)(w_lds + ((kstep * 2 + 0) * 64 + lane) * 8);
            const short8_t* wp1 = (const short8_t*)(w_lds + ((kstep * 2 + 1) * 64 + lane) * 8);
            acc0 = __builtin_amdgcn_mfma_f32_16x16x32_bf16(*wp0, gf, acc0, 0, 0, 0);
            acc1 = __builtin_amdgcn_mfma_f32_16x16x32_bf16(*wp1, gf, acc1, 0, 0, 0);
        }

        int vr = tl * 64 + wave * 16 + m;
        if (vr < V_OUT) {
            float4 o0, o1;
            o0.x = acc0[0] + bias0.x; o0.y = acc0[1] + bias0.y;
            o0.z = acc0[2] + bias0.z; o0.w = acc0[3] + bias0.w;
            o1.x = acc1[0] + bias1.x; o1.y = acc1[1] + bias1.y;
            o1.z = acc1[2] + bias1.z; o1.w = acc1[3] + bias1.w;
            o0.x = o0.x > 0.f ? o0.x : 0.f;  o0.y = o0.y > 0.f ? o0.y : 0.f;
            o0.z = o0.z > 0.f ? o0.z : 0.f;  o0.w = o0.w > 0.f ? o0.w : 0.f;
            o1.x = o1.x > 0.f ? o1.x : 0.f;  o1.y = o1.y > 0.f ? o1.y : 0.f;
            o1.z = o1.z > 0.f ? o1.z : 0.f;  o1.w = o1.w > 0.f ? o1.w : 0.f;
            float* op = outb + (size_t)vr * C_OUT;
            *(float4*)(op + quad * 4)      = o0;
            *(float4*)(op + 16 + quad * 4) = o1;
        }
    }
}

extern "C" void kernel_launch(void* const* d_in, const int* in_sizes, int n_in,
                              void* d_out, int out_size, void* d_ws, size_t ws_size,
                              hipStream_t stream) {
    const float* x      = (const float*)d_in[0];
    const int*   spiral = (const int*)d_in[1];
    const int*   up_idx = (const int*)d_in[2];
    const float* up_val = (const float*)d_in[3];
    const float* weight = (const float*)d_in[4];
    const float* bias   = (const float*)d_in[5];
    float* out = (float*)d_out;

    unsigned short* up_ws  = (unsigned short*)d_ws;          // 200000*64 bf16 = 25.6 MB
    unsigned short* w_frag = up_ws + (size_t)ROWS * C_IN;    // + 36864 B

    upsample_kernel<<<G1 + 1, 256, 0, stream>>>(x, up_idx, up_val, weight, up_ws, w_frag);
    gemm_kernel<<<G2, 256, 0, stream>>>(up_ws, spiral, w_frag, bias, out);
}